// Round 3
// baseline (900.561 us; speedup 1.0000x reference)
//
#include <hip/hip_runtime.h>
#include <stdint.h>

typedef int   v4i __attribute__((ext_vector_type(4)));
typedef float v4f __attribute__((ext_vector_type(4)));

// LDS map (no weights in LDS anymore):
//   [0, 2*13824)  act slots: hi at l*2304 + b*144 + k, lo at +6912
//   BIAS_OFF      fp32 bias [l][type R,Z,NX,NH][h]  (6144 B)
//   FC_OFF        fc i8 A-frags, 2 blocks of 1KB
#define SLOT_SZ  13824
#define LO_OFF   6912
#define BIAS_OFF (2*SLOT_SZ)            // 27648
#define FC_OFF   (BIAS_OFF + 6144)      // 33792
#define SMEM_SZ  (FC_OFF + 2048)        // 35840 (<64K, no opt-in needed)

#define QW   1436.84056f      // 127/s, s = 1/sqrt(128)
#define C1f  4.38394754e-5f   // s*8/127^2  (hi-accum scale)
#define C2f  3.45193507e-7f   // C1/127     (lo-accum scale)

__device__ __forceinline__ float sigm(float x) {
  return __builtin_amdgcn_rcpf(1.f + __expf(-x));
}
__device__ __forceinline__ float tanh_(float x) {
  return 1.f - 2.f * __builtin_amdgcn_rcpf(1.f + __expf(2.f * x));
}

// i8 weight image (UNCHANGED from R2; A-frag == B-frag lane layout for 16x16):
// blk = l*12 + o*2 + kh; o: 0 Rx,1 Rh,2 Zx,3 Zh,4 Nx,5 Nh.
// lane(g=lane&15, q=lane>>4) holds W[row g][k = kh*64 + q*16 + j], j=0..15.
__global__ void prep_weights(const float* __restrict__ Wih,
                             const float* __restrict__ Whh,
                             int8_t* __restrict__ img) {
  int bid = blockIdx.x, lane = threadIdx.x;          // 288 blocks x 64
  int w = bid / 36, blk = bid % 36;
  int l = blk / 12, rem = blk % 12, o = rem >> 1, kh = rem & 1;
  const float* M = (o & 1) ? Whh : Wih;
  int row = (o >> 1) * 128 + w * 16 + (lane & 15);
  int k0 = kh * 64 + (lane >> 4) * 16;
  const float* src = M + l * 49152 + row * 128 + k0;
  int words[4];
  #pragma unroll
  for (int j4 = 0; j4 < 4; ++j4) {
    unsigned wd = 0;
    #pragma unroll
    for (int j = 0; j < 4; ++j) {
      int q = (int)rintf(src[j4 * 4 + j] * QW);
      wd |= ((unsigned)(q & 255)) << (8 * j);
    }
    words[j4] = (int)wd;
  }
  *(v4i*)(img + (((long)bid) * 64 + lane) * 16) = *(const v4i*)words;
}

__device__ __forceinline__ unsigned pack_hi(const float* f, const float* fhi) {
  unsigned wd = 0;
  #pragma unroll
  for (int r = 0; r < 4; ++r) {
    int v = (int)fhi[r];
    wd |= ((unsigned)(v & 255)) << (8 * r);
  }
  return wd;
}

__global__ __launch_bounds__(512, 2)
void gru_main(const float* __restrict__ hiddens, const float* __restrict__ bih,
              const float* __restrict__ bhh, const float* __restrict__ fcw,
              const float* __restrict__ fcb, const int8_t* __restrict__ img,
              float* __restrict__ out) {
  extern __shared__ char smem[];
  const int tid = threadIdx.x, wg = blockIdx.x;
  const int lane = tid & 63, w = tid >> 6, col = lane & 15, q = lane >> 4;

  // ---- ALL 36 weight frags in registers (144 regs) ----
  v4i wr[36];
  #pragma unroll
  for (int i = 0; i < 36; ++i)
    wr[i] = *(const v4i*)(img + (((long)(w * 36 + i)) * 64 + lane) * 16);

  // ---- fc i8 A-frags in LDS (2 blocks; rows>=2 zero) ----
  if (tid < 128) {
    int kh = tid >> 6, ln = tid & 63, c2 = ln & 15, q2 = ln >> 4;
    int words[4] = {0, 0, 0, 0};
    if (c2 < 2) {
      const float* src = fcw + c2 * 128 + kh * 64 + q2 * 16;
      #pragma unroll
      for (int j4 = 0; j4 < 4; ++j4) {
        unsigned wd = 0;
        #pragma unroll
        for (int j = 0; j < 4; ++j) {
          int qv = (int)rintf(src[j4 * 4 + j] * QW);
          wd |= ((unsigned)(qv & 255)) << (8 * j);
        }
        words[j4] = (int)wd;
      }
    }
    *(v4i*)(smem + FC_OFF + kh * 1024 + ln * 16) = *(const v4i*)words;
  }
  // ---- bias table in LDS: [l][type][h] fp32 ----
  for (int i = tid; i < 1536; i += 512) {
    int l = i >> 9, type = (i >> 7) & 3, h = i & 127;
    float bv;
    if      (type == 0) bv = bih[l * 384 + h]       + bhh[l * 384 + h];
    else if (type == 1) bv = bih[l * 384 + 128 + h] + bhh[l * 384 + 128 + h];
    else if (type == 2) bv = bih[l * 384 + 256 + h];
    else                bv = bhh[l * 384 + 256 + h];
    *(float*)(smem + BIAS_OFF + i * 4) = bv;
  }
  // ---- act slot0 init (hi/lo) ----
  for (int i = tid; i < 6144; i += 512) {
    int l = i >> 11, b = (i >> 7) & 15, h = i & 127;
    float v = hiddens[((long)(wg * 16 + b)) * 384 + l * 128 + h];
    float f = v * 15.875f, fhi = rintf(f);
    *(int8_t*)(smem + l * 2304 + b * 144 + h)          = (int8_t)(int)fhi;
    *(int8_t*)(smem + l * 2304 + b * 144 + h + LO_OFF) = (int8_t)(int)rintf((f - fhi) * 127.f);
  }
  // ---- h-state in regs: hst[l][r] = h[l][w*16+q*4+r][batch=col] ----
  v4f hst[3];
  #pragma unroll
  for (int l = 0; l < 3; ++l)
    #pragma unroll
    for (int r = 0; r < 4; ++r)
      hst[l][r] = hiddens[((long)(wg * 16 + col)) * 384 + l * 128 + w * 16 + q * 4 + r];

  const float fcb0 = fcb[0], fcb1 = fcb[1];
  __syncthreads();

  const char* fragb = smem + col * 144 + q * 16;   // B-frag lane base (n=col=batch)
  char* ewb = smem + col * 144 + w * 16 + q * 4;   // EW b32 write base
  const char* biasb = smem + BIAS_OFF + (w * 16 + q * 4) * 4;

  v4i c2h[2], c2l[2];   // cached layer-2 read-slot frags (l0-x == l2-h data)

  #pragma unroll 1
  for (int t = 0; t < 256; ++t) {
    const int so = (t & 1) * SLOT_SZ;
    const int sn = SLOT_SZ - so;
    #pragma unroll
    for (int l = 0; l < 3; ++l) {
      v4i aRh = {0,0,0,0}, aRl = {0,0,0,0}, aZh = {0,0,0,0}, aZl = {0,0,0,0};
      v4i aXh = {0,0,0,0}, aXl = {0,0,0,0}, aHh = {0,0,0,0}, aHl = {0,0,0,0};
      // ---- x side ----
      if (l > 0 || t > 0) {
        #pragma unroll
        for (int kh = 0; kh < 2; ++kh) {
          v4i xh, xl;
          if (l == 0) {           // x = prev-step layer2 acts (read slot); cache
            xh = *(const v4i*)(fragb + so + 2 * 2304 + kh * 64);
            xl = *(const v4i*)(fragb + so + 2 * 2304 + kh * 64 + LO_OFF);
            c2h[kh] = xh; c2l[kh] = xl;
          } else {                // x = fresh layer l-1 acts (write slot)
            xh = *(const v4i*)(fragb + sn + (l - 1) * 2304 + kh * 64);
            xl = *(const v4i*)(fragb + sn + (l - 1) * 2304 + kh * 64 + LO_OFF);
          }
          aRh = __builtin_amdgcn_mfma_i32_16x16x64_i8(wr[l*12 + 0 + kh], xh, aRh, 0, 0, 0);
          aRl = __builtin_amdgcn_mfma_i32_16x16x64_i8(wr[l*12 + 0 + kh], xl, aRl, 0, 0, 0);
          aZh = __builtin_amdgcn_mfma_i32_16x16x64_i8(wr[l*12 + 4 + kh], xh, aZh, 0, 0, 0);
          aZl = __builtin_amdgcn_mfma_i32_16x16x64_i8(wr[l*12 + 4 + kh], xl, aZl, 0, 0, 0);
          aXh = __builtin_amdgcn_mfma_i32_16x16x64_i8(wr[l*12 + 8 + kh], xh, aXh, 0, 0, 0);
          aXl = __builtin_amdgcn_mfma_i32_16x16x64_i8(wr[l*12 + 8 + kh], xl, aXl, 0, 0, 0);
        }
      }
      // ---- h side ----
      #pragma unroll
      for (int kh = 0; kh < 2; ++kh) {
        v4i hh, hl;
        if (l == 2) {             // same bytes l0-x read this step
          if (t == 0) { c2h[kh] = *(const v4i*)(fragb + so + 2 * 2304 + kh * 64);
                        c2l[kh] = *(const v4i*)(fragb + so + 2 * 2304 + kh * 64 + LO_OFF); }
          hh = c2h[kh]; hl = c2l[kh];
        } else {
          hh = *(const v4i*)(fragb + so + l * 2304 + kh * 64);
          hl = *(const v4i*)(fragb + so + l * 2304 + kh * 64 + LO_OFF);
        }
        aRh = __builtin_amdgcn_mfma_i32_16x16x64_i8(wr[l*12 + 2 + kh], hh, aRh, 0, 0, 0);
        aRl = __builtin_amdgcn_mfma_i32_16x16x64_i8(wr[l*12 + 2 + kh], hl, aRl, 0, 0, 0);
        aZh = __builtin_amdgcn_mfma_i32_16x16x64_i8(wr[l*12 + 6 + kh], hh, aZh, 0, 0, 0);
        aZl = __builtin_amdgcn_mfma_i32_16x16x64_i8(wr[l*12 + 6 + kh], hl, aZl, 0, 0, 0);
        aHh = __builtin_amdgcn_mfma_i32_16x16x64_i8(wr[l*12 + 10 + kh], hh, aHh, 0, 0, 0);
        aHl = __builtin_amdgcn_mfma_i32_16x16x64_i8(wr[l*12 + 10 + kh], hl, aHl, 0, 0, 0);
      }
      // ---- EW: biases from LDS broadcast, fp32 state, packed b32 writes ----
      v4f bRv = *(const v4f*)(biasb + (l * 4 + 0) * 512);
      v4f bZv = *(const v4f*)(biasb + (l * 4 + 1) * 512);
      v4f bXv = *(const v4f*)(biasb + (l * 4 + 2) * 512);
      v4f bHv = *(const v4f*)(biasb + (l * 4 + 3) * 512);
      unsigned hiw = 0, low = 0;
      #pragma unroll
      for (int r = 0; r < 4; ++r) {
        float gR = bRv[r] + C1f * (float)aRh[r] + C2f * (float)aRl[r];
        float gZ = bZv[r] + C1f * (float)aZh[r] + C2f * (float)aZl[r];
        float gX = bXv[r] + C1f * (float)aXh[r] + C2f * (float)aXl[r];
        float gH = bHv[r] + C1f * (float)aHh[r] + C2f * (float)aHl[r];
        float rg = sigm(gR), zg = sigm(gZ);
        float ng = tanh_(gX + rg * gH);
        float hn = ng + zg * (hst[l][r] - ng);
        hst[l][r] = hn;
        float f = hn * 15.875f, fhi = rintf(f);
        hiw |= ((unsigned)(((int)fhi) & 255)) << (8 * r);
        low |= ((unsigned)(((int)rintf((f - fhi) * 127.f)) & 255)) << (8 * r);
      }
      *(unsigned*)(ewb + sn + l * 2304)          = hiw;
      *(unsigned*)(ewb + sn + l * 2304 + LO_OFF) = low;
      __syncthreads();
    }
    // ---- FC epilogue (wave 0): D = fcw(A) . act_l2_new(B) ----
    if (w == 0) {
      v4i dh = {0,0,0,0}, dl = {0,0,0,0};
      #pragma unroll
      for (int kh = 0; kh < 2; ++kh) {
        v4i xh = *(const v4i*)(fragb + sn + 2 * 2304 + kh * 64);
        v4i xl = *(const v4i*)(fragb + sn + 2 * 2304 + kh * 64 + LO_OFF);
        v4i fw = *(const v4i*)(smem + FC_OFF + kh * 1024 + lane * 16);
        dh = __builtin_amdgcn_mfma_i32_16x16x64_i8(fw, xh, dh, 0, 0, 0);
        dl = __builtin_amdgcn_mfma_i32_16x16x64_i8(fw, xl, dl, 0, 0, 0);
      }
      if (q == 0) {               // rows m=0,1 live in q=0, r=0,1
        float2 o2;
        o2.x = fcb0 + C1f * (float)dh[0] + C2f * (float)dl[0];
        o2.y = fcb1 + C1f * (float)dh[1] + C2f * (float)dl[1];
        *(float2*)(out + (((long)(wg * 16 + col)) * 256 + t) * 2) = o2;
      }
    }
  }
}

extern "C" void kernel_launch(void* const* d_in, const int* in_sizes, int n_in,
                              void* d_out, int out_size, void* d_ws, size_t ws_size,
                              hipStream_t stream) {
  (void)in_sizes; (void)n_in; (void)out_size; (void)ws_size;
  const float* hiddens = (const float*)d_in[0];
  const float* Wih     = (const float*)d_in[1];
  const float* Whh     = (const float*)d_in[2];
  const float* bih     = (const float*)d_in[3];
  const float* bhh     = (const float*)d_in[4];
  const float* fcw     = (const float*)d_in[5];
  const float* fcb     = (const float*)d_in[6];
  int8_t* img = (int8_t*)d_ws;   // 288 KB weight image
  float* out = (float*)d_out;

  prep_weights<<<288, 64, 0, stream>>>(Wih, Whh, img);
  gru_main<<<64, 512, SMEM_SZ, stream>>>(hiddens, bih, bhh, fcw, fcb, img, out);
}